// Round 1
// baseline (694.348 us; speedup 1.0000x reference)
//
#include <hip/hip_runtime.h>

#define LEAKY_ATT 0.2f
#define LEAKY_ACT 0.01f

__device__ __forceinline__ float leaky(float x, float s) { return x >= 0.f ? x : s * x; }

// ============================ CSR build (by dst) ============================
__global__ void k_hist(const int* __restrict__ dst, int e, int* __restrict__ deg) {
  for (int i = blockIdx.x * blockDim.x + threadIdx.x; i < e; i += gridDim.x * blockDim.x)
    atomicAdd(&deg[dst[i]], 1);
}

__global__ __launch_bounds__(256) void k_scan1(const int* __restrict__ deg, int n,
                                               int* __restrict__ partial, int* __restrict__ bsum) {
  __shared__ int sh[256];
  int t = threadIdx.x;
  int i = blockIdx.x * 256 + t;
  sh[t] = (i < n) ? deg[i] : 0;
  __syncthreads();
  for (int off = 1; off < 256; off <<= 1) {
    int v = (t >= off) ? sh[t - off] : 0;
    __syncthreads();
    sh[t] += v;
    __syncthreads();
  }
  if (i < n) partial[i] = sh[t];
  if (t == 255) bsum[blockIdx.x] = sh[255];
}

__global__ __launch_bounds__(512) void k_scan2(int* __restrict__ bsum, int nb) {
  __shared__ int sh[512];
  int t = threadIdx.x;
  sh[t] = (t < nb) ? bsum[t] : 0;
  __syncthreads();
  for (int off = 1; off < 512; off <<= 1) {
    int v = (t >= off) ? sh[t - off] : 0;
    __syncthreads();
    sh[t] += v;
    __syncthreads();
  }
  if (t < nb) bsum[t] = sh[t];
}

__global__ __launch_bounds__(256) void k_scan3(const int* __restrict__ partial,
                                               const int* __restrict__ deg,
                                               const int* __restrict__ bscan, int n,
                                               int* __restrict__ rowptr, int* __restrict__ cursor) {
  int b = blockIdx.x;
  int i = b * 256 + threadIdx.x;
  if (i >= n) return;
  int off = (b > 0) ? bscan[b - 1] : 0;
  int inc = partial[i] + off;
  rowptr[i + 1] = inc;
  cursor[i] = inc - deg[i];
  if (i == 0) rowptr[0] = 0;
}

__global__ void k_scatter(const int* __restrict__ src, const int* __restrict__ dst, int e,
                          int* __restrict__ cursor, int* __restrict__ col) {
  for (int i = blockIdx.x * blockDim.x + threadIdx.x; i < e; i += gridDim.x * blockDim.x) {
    int p = atomicAdd(&cursor[dst[i]], 1);
    col[p] = src[i];
  }
}

// ============================ weight prep ============================
// vsd[k][i], i<8: v_src (head i), i>=8: v_dst (head i-8)
__global__ void k_prep_vsd(const float* __restrict__ wsrc, const float* __restrict__ wdst,
                           const float* __restrict__ asrc, const float* __restrict__ adst,
                           float* __restrict__ vsd) {
  int k = blockIdx.x;   // 0..127
  int i = threadIdx.x;  // 0..15
  float s = 0.f;
  if (i < 8) {
    for (int c = 0; c < 16; ++c) s += wsrc[k * 128 + i * 16 + c] * asrc[i * 16 + c];
  } else {
    int h = i - 8;
    for (int c = 0; c < 16; ++c) s += wdst[k * 128 + h * 16 + c] * adst[h * 16 + c];
  }
  vsd[k * 16 + i] = s;
}

// U[k][0..1] = w3_src[k][0..1]; U[k][2] = sum_c w3_src[k][c]*a3_src[c]; U[k][3] = dst analog
__global__ void k_prep_u3(const float* __restrict__ w3s, const float* __restrict__ w3d,
                          const float* __restrict__ a3s, const float* __restrict__ a3d,
                          float* __restrict__ U) {
  int k = blockIdx.x * blockDim.x + threadIdx.x;
  if (k >= 128) return;
  U[k * 4 + 0] = w3s[k * 2 + 0];
  U[k * 4 + 1] = w3s[k * 2 + 1];
  U[k * 4 + 2] = w3s[k * 2 + 0] * a3s[0] + w3s[k * 2 + 1] * a3s[1];
  U[k * 4 + 3] = w3d[k * 2 + 0] * a3d[0] + w3d[k * 2 + 1] * a3d[1];
}

// ============================ layer 1/2 linear: xs = X@W, al = X@vsd ============================
__global__ __launch_bounds__(256) void k_gemm_xs_al(const float* __restrict__ X,
                                                    const float* __restrict__ W,
                                                    const float* __restrict__ VSD,
                                                    float* __restrict__ XS,
                                                    float* __restrict__ AL, int n) {
  __shared__ float xt[64][128];  // 32 KB
  int t = threadIdx.x;
  int row0 = blockIdx.x * 64;
  for (int i = t; i < 64 * 128; i += 256) {
    int r = i >> 7, c = i & 127;
    int gr = row0 + r;
    xt[r][c] = (gr < n) ? X[gr * 128 + c] : 0.f;
  }
  __syncthreads();

  // main GEMM: each thread 8 rows x 4 cols
  int c0 = (t & 31) * 4;
  int r0 = (t >> 5) * 8;
  float acc[8][4] = {};
  for (int k = 0; k < 128; ++k) {
    float4 wv = *reinterpret_cast<const float4*>(&W[k * 128 + c0]);
#pragma unroll
    for (int i = 0; i < 8; ++i) {
      float xv = xt[r0 + i][k];
      acc[i][0] += xv * wv.x;
      acc[i][1] += xv * wv.y;
      acc[i][2] += xv * wv.z;
      acc[i][3] += xv * wv.w;
    }
  }
#pragma unroll
  for (int i = 0; i < 8; ++i) {
    int gr = row0 + r0 + i;
    if (gr < n) {
      float4 v = make_float4(acc[i][0], acc[i][1], acc[i][2], acc[i][3]);
      *reinterpret_cast<float4*>(&XS[gr * 128 + c0]) = v;
    }
  }

  // attention logits: thread -> node t>>2, combos j0..j0+3 of 16
  int node = t >> 2;
  int j0 = (t & 3) * 4;
  float a[4] = {};
  for (int k = 0; k < 128; ++k) {
    float xv = xt[node][k];
#pragma unroll
    for (int j = 0; j < 4; ++j) a[j] += xv * VSD[k * 16 + j0 + j];
  }
  int gr = row0 + node;
  if (gr < n) {
#pragma unroll
    for (int j = 0; j < 4; ++j) AL[gr * 16 + j0 + j] = a[j];
  }
}

// ============================ layer 1/2 aggregation ============================
// one block (128 threads) per dst node; thread = channel c, head h = c>>4
__global__ __launch_bounds__(128) void k_gat_agg(const float* __restrict__ XS,
                                                 const float* __restrict__ AL,
                                                 const int* __restrict__ rowptr,
                                                 const int* __restrict__ col,
                                                 const float* __restrict__ bias,
                                                 float* __restrict__ OUT, int n, int act) {
  int node = blockIdx.x;
  int t = threadIdx.x;
  int h = t >> 4;
  __shared__ int srcs[128];
  __shared__ float ald_sh[8];
  if (t < 8) ald_sh[t] = AL[node * 16 + 8 + t];
  __syncthreads();
  float al_dn = ald_sh[h];

  // self loop
  float e0 = leaky(AL[node * 16 + h] + al_dn, LEAKY_ATT);
  float w0 = __expf(e0);
  float den = w0;
  float acc = w0 * XS[node * 128 + t];

  int beg = rowptr[node], end = rowptr[node + 1];
  for (int base = beg; base < end; base += 128) {
    int cnt = min(128, end - base);
    if (t < cnt) srcs[t] = col[base + t];
    __syncthreads();
    for (int j = 0; j < cnt; ++j) {
      int s = srcs[j];
      float ee = leaky(AL[s * 16 + h] + al_dn, LEAKY_ATT);
      float w = __expf(ee);
      den += w;
      acc += w * XS[s * 128 + t];
    }
    __syncthreads();
  }
  float o = acc / den + bias[t];
  if (act) o = leaky(o, LEAKY_ACT);
  OUT[node * 128 + t] = o;
}

// ============================ layer 3 ============================
// XSAL3[n][4] = {xs0, xs1, al_s, al_d}
__global__ __launch_bounds__(256) void k_lin3(const float* __restrict__ X,
                                              const float* __restrict__ U,
                                              float* __restrict__ XSAL3, int n) {
  __shared__ float xt[64][128];
  int t = threadIdx.x;
  int row0 = blockIdx.x * 64;
  for (int i = t; i < 64 * 128; i += 256) {
    int r = i >> 7, c = i & 127;
    int gr = row0 + r;
    xt[r][c] = (gr < n) ? X[gr * 128 + c] : 0.f;
  }
  __syncthreads();
  int node = t >> 2;
  int j = t & 3;
  float a = 0.f;
  for (int k = 0; k < 128; ++k) a += xt[node][k] * U[k * 4 + j];
  int gr = row0 + node;
  if (gr < n) XSAL3[gr * 4 + j] = a;
}

__global__ __launch_bounds__(256) void k_agg3(const float* __restrict__ XSAL3,
                                              const int* __restrict__ rowptr,
                                              const int* __restrict__ col,
                                              const float* __restrict__ b3,
                                              float* __restrict__ out, int n) {
  int node = blockIdx.x * blockDim.x + threadIdx.x;
  if (node >= n) return;
  float4 self = *reinterpret_cast<const float4*>(&XSAL3[node * 4]);
  float ald = self.w;
  float e0 = leaky(self.z + ald, LEAKY_ATT);
  float w0 = __expf(e0);
  float den = w0;
  float a0 = w0 * self.x;
  float a1 = w0 * self.y;
  int end = rowptr[node + 1];
  for (int jj = rowptr[node]; jj < end; ++jj) {
    int s = col[jj];
    float4 v = *reinterpret_cast<const float4*>(&XSAL3[s * 4]);
    float ee = leaky(v.z + ald, LEAKY_ATT);
    float w = __expf(ee);
    den += w;
    a0 += w * v.x;
    a1 += w * v.y;
  }
  out[node * 2 + 0] = a0 / den + b3[0];
  out[node * 2 + 1] = a1 / den + b3[1];
}

// ============================ launch ============================
extern "C" void kernel_launch(void* const* d_in, const int* in_sizes, int n_in,
                              void* d_out, int out_size, void* d_ws, size_t ws_size,
                              hipStream_t stream) {
  const float* x = (const float*)d_in[0];
  const int* ei = (const int*)d_in[1];
  const float* w1s = (const float*)d_in[2];
  const float* w1d = (const float*)d_in[3];
  const float* a1s = (const float*)d_in[4];
  const float* a1d = (const float*)d_in[5];
  const float* b1 = (const float*)d_in[6];
  const float* w2s = (const float*)d_in[7];
  const float* w2d = (const float*)d_in[8];
  const float* a2s = (const float*)d_in[9];
  const float* a2d = (const float*)d_in[10];
  const float* b2 = (const float*)d_in[11];
  const float* w3s = (const float*)d_in[12];
  const float* w3d = (const float*)d_in[13];
  const float* a3s = (const float*)d_in[14];
  const float* a3d = (const float*)d_in[15];
  const float* b3 = (const float*)d_in[16];

  int n = in_sizes[0] / 128;
  int e = in_sizes[1] / 2;
  const int* srcp = ei;
  const int* dstp = ei + e;

  // workspace carve
  size_t off = 0;
  auto alloc = [&](size_t bytes) -> void* {
    void* p = (char*)d_ws + off;
    off += (bytes + 255) & ~(size_t)255;
    return p;
  };
  int* deg = (int*)alloc((size_t)n * 4);
  int* cursor = (int*)alloc((size_t)n * 4);
  int* rowptr = (int*)alloc((size_t)(n + 1) * 4);
  int* partial = (int*)alloc((size_t)n * 4);
  int* bsum = (int*)alloc(1024 * 4);
  int* col = (int*)alloc((size_t)e * 4);
  float* vsd1 = (float*)alloc(128 * 16 * 4);
  float* vsd2 = (float*)alloc(128 * 16 * 4);
  float* u3 = (float*)alloc(128 * 4 * 4);
  float* al = (float*)alloc((size_t)n * 16 * 4);
  float* xs = (float*)alloc((size_t)n * 128 * 4);
  float* ha = (float*)alloc((size_t)n * 128 * 4);
  float* xsal3 = (float*)alloc((size_t)n * 4 * 4);
  if (off > ws_size) return;  // workspace too small -> fail validation cleanly

  int nb = (n + 255) / 256;

  // CSR build (edge structure shared across all 3 layers)
  hipMemsetAsync(deg, 0, (size_t)n * 4, stream);
  k_hist<<<2048, 256, 0, stream>>>(dstp, e, deg);
  k_scan1<<<nb, 256, 0, stream>>>(deg, n, partial, bsum);
  k_scan2<<<1, 512, 0, stream>>>(bsum, nb);
  k_scan3<<<nb, 256, 0, stream>>>(partial, deg, bsum, n, rowptr, cursor);
  k_scatter<<<2048, 256, 0, stream>>>(srcp, dstp, e, cursor, col);

  // weight prep
  k_prep_vsd<<<128, 16, 0, stream>>>(w1s, w1d, a1s, a1d, vsd1);
  k_prep_vsd<<<128, 16, 0, stream>>>(w2s, w2d, a2s, a2d, vsd2);
  k_prep_u3<<<1, 128, 0, stream>>>(w3s, w3d, a3s, a3d, u3);

  int gb = (n + 63) / 64;
  // layer 1
  k_gemm_xs_al<<<gb, 256, 0, stream>>>(x, w1s, vsd1, xs, al, n);
  k_gat_agg<<<n, 128, 0, stream>>>(xs, al, rowptr, col, b1, ha, n, 1);
  // layer 2
  k_gemm_xs_al<<<gb, 256, 0, stream>>>(ha, w2s, vsd2, xs, al, n);
  k_gat_agg<<<n, 128, 0, stream>>>(xs, al, rowptr, col, b2, ha, n, 1);
  // layer 3
  k_lin3<<<gb, 256, 0, stream>>>(ha, u3, xsal3, n);
  k_agg3<<<(n + 255) / 256, 256, 0, stream>>>(xsal3, rowptr, col, b3, (float*)d_out, n);
}

// Round 2
// 645.599 us; speedup vs baseline: 1.0755x; 1.0755x over previous
//
#include <hip/hip_runtime.h>
#include <hip/hip_bf16.h>

#define LEAKY_ATT 0.2f
#define LEAKY_ACT 0.01f

__device__ __forceinline__ float leaky(float x, float s) { return x >= 0.f ? x : s * x; }

__device__ __forceinline__ uint f2bf(float f) {
  __hip_bfloat16 h = __float2bfloat16(f);  // RTNE
  return (uint)*reinterpret_cast<ushort*>(&h);
}

// ============================ CSR build (by dst) ============================
__global__ void k_hist(const int* __restrict__ dst, int e, int* __restrict__ deg) {
  for (int i = blockIdx.x * blockDim.x + threadIdx.x; i < e; i += gridDim.x * blockDim.x)
    atomicAdd(&deg[dst[i]], 1);
}

__global__ __launch_bounds__(256) void k_scan1(const int* __restrict__ deg, int n,
                                               int* __restrict__ partial, int* __restrict__ bsum) {
  __shared__ int sh[256];
  int t = threadIdx.x;
  int i = blockIdx.x * 256 + t;
  sh[t] = (i < n) ? deg[i] : 0;
  __syncthreads();
  for (int off = 1; off < 256; off <<= 1) {
    int v = (t >= off) ? sh[t - off] : 0;
    __syncthreads();
    sh[t] += v;
    __syncthreads();
  }
  if (i < n) partial[i] = sh[t];
  if (t == 255) bsum[blockIdx.x] = sh[255];
}

__global__ __launch_bounds__(512) void k_scan2(int* __restrict__ bsum, int nb) {
  __shared__ int sh[512];
  int t = threadIdx.x;
  sh[t] = (t < nb) ? bsum[t] : 0;
  __syncthreads();
  for (int off = 1; off < 512; off <<= 1) {
    int v = (t >= off) ? sh[t - off] : 0;
    __syncthreads();
    sh[t] += v;
    __syncthreads();
  }
  if (t < nb) bsum[t] = sh[t];
}

__global__ __launch_bounds__(256) void k_scan3(const int* __restrict__ partial,
                                               const int* __restrict__ deg,
                                               const int* __restrict__ bscan, int n,
                                               int* __restrict__ rowptr, int* __restrict__ cursor) {
  int b = blockIdx.x;
  int i = b * 256 + threadIdx.x;
  if (i >= n) return;
  int off = (b > 0) ? bscan[b - 1] : 0;
  int inc = partial[i] + off;
  rowptr[i + 1] = inc;
  cursor[i] = inc - deg[i];
  if (i == 0) rowptr[0] = 0;
}

__global__ void k_scatter(const int* __restrict__ src, const int* __restrict__ dst, int e,
                          int* __restrict__ cursor, int* __restrict__ col) {
  for (int i = blockIdx.x * blockDim.x + threadIdx.x; i < e; i += gridDim.x * blockDim.x) {
    int p = atomicAdd(&cursor[dst[i]], 1);
    col[p] = src[i];
  }
}

// ============================ weight prep ============================
__global__ void k_prep_vsd(const float* __restrict__ wsrc, const float* __restrict__ wdst,
                           const float* __restrict__ asrc, const float* __restrict__ adst,
                           float* __restrict__ vsd) {
  int k = blockIdx.x;   // 0..127
  int i = threadIdx.x;  // 0..15
  float s = 0.f;
  if (i < 8) {
    for (int c = 0; c < 16; ++c) s += wsrc[k * 128 + i * 16 + c] * asrc[i * 16 + c];
  } else {
    int h = i - 8;
    for (int c = 0; c < 16; ++c) s += wdst[k * 128 + h * 16 + c] * adst[h * 16 + c];
  }
  vsd[k * 16 + i] = s;
}

__global__ void k_prep_u3(const float* __restrict__ w3s, const float* __restrict__ w3d,
                          const float* __restrict__ a3s, const float* __restrict__ a3d,
                          float* __restrict__ U) {
  int k = blockIdx.x * blockDim.x + threadIdx.x;
  if (k >= 128) return;
  U[k * 4 + 0] = w3s[k * 2 + 0];
  U[k * 4 + 1] = w3s[k * 2 + 1];
  U[k * 4 + 2] = w3s[k * 2 + 0] * a3s[0] + w3s[k * 2 + 1] * a3s[1];
  U[k * 4 + 3] = w3d[k * 2 + 0] * a3d[0] + w3d[k * 2 + 1] * a3d[1];
}

// ============================ layer 1/2 linear: XSb(bf16) = X@W, AL = X@vsd ============================
__global__ __launch_bounds__(256) void k_gemm_xs_al(const float* __restrict__ X,
                                                    const float* __restrict__ W,
                                                    const float* __restrict__ VSD,
                                                    ushort* __restrict__ XSb,
                                                    float* __restrict__ AL, int n) {
  __shared__ float xt[64][128];  // 32 KB
  int t = threadIdx.x;
  int row0 = blockIdx.x * 64;
  for (int i = t; i < 64 * 128; i += 256) {
    int r = i >> 7, c = i & 127;
    int gr = row0 + r;
    xt[r][c] = (gr < n) ? X[gr * 128 + c] : 0.f;
  }
  __syncthreads();

  int c0 = (t & 31) * 4;
  int r0 = (t >> 5) * 8;
  float acc[8][4] = {};
  for (int k = 0; k < 128; ++k) {
    float4 wv = *reinterpret_cast<const float4*>(&W[k * 128 + c0]);
#pragma unroll
    for (int i = 0; i < 8; ++i) {
      float xv = xt[r0 + i][k];
      acc[i][0] += xv * wv.x;
      acc[i][1] += xv * wv.y;
      acc[i][2] += xv * wv.z;
      acc[i][3] += xv * wv.w;
    }
  }
#pragma unroll
  for (int i = 0; i < 8; ++i) {
    int gr = row0 + r0 + i;
    if (gr < n) {
      uint lo = f2bf(acc[i][0]) | (f2bf(acc[i][1]) << 16);
      uint hi = f2bf(acc[i][2]) | (f2bf(acc[i][3]) << 16);
      *reinterpret_cast<uint2*>(&XSb[(size_t)gr * 128 + c0]) = make_uint2(lo, hi);
    }
  }

  // attention logits
  int node = t >> 2;
  int j0 = (t & 3) * 4;
  float a[4] = {};
  for (int k = 0; k < 128; ++k) {
    float xv = xt[node][k];
#pragma unroll
    for (int j = 0; j < 4; ++j) a[j] += xv * VSD[k * 16 + j0 + j];
  }
  int gr = row0 + node;
  if (gr < n) {
#pragma unroll
    for (int j = 0; j < 4; ++j) AL[gr * 16 + j0 + j] = a[j];
  }
}

// ============================ layer 1/2 aggregation ============================
// block = 128 threads per dst node.
// phase A: 32 edges x 8 heads weights into LDS (1 exp per thread per 16 edges)
// phase B: 4 edges in flight; thread = (slot = t>>5, chan group c0 = (t&31)*4), uint2 bf16 loads
__global__ __launch_bounds__(128) void k_gat_agg(const ushort* __restrict__ XSb,
                                                 const float* __restrict__ AL,
                                                 const int* __restrict__ rowptr,
                                                 const int* __restrict__ col,
                                                 const float* __restrict__ bias,
                                                 float* __restrict__ OUT, int n, int act) {
  int node = blockIdx.x;
  int t = threadIdx.x;
  int slot = t >> 5;
  int lane = t & 31;
  int c0 = lane * 4;
  int hd = lane >> 2;  // c0/16

  __shared__ int srcs[32];
  __shared__ float wsh[32][8];
  __shared__ float4 accsh[4][32];
  __shared__ float densh[4][32];
  __shared__ float ald_sh[8];

  if (t < 8) ald_sh[t] = AL[node * 16 + 8 + t];
  __syncthreads();

  float4 acc = make_float4(0.f, 0.f, 0.f, 0.f);
  float den = 0.f;

  int beg = rowptr[node], end = rowptr[node + 1];
  for (int base = beg; base < end; base += 32) {
    int cnt = min(32, end - base);
    if (t < cnt) srcs[t] = col[base + t];
    __syncthreads();

    // phase A: weights
    {
      int ha = t & 7;
#pragma unroll
      for (int p = 0; p < 2; ++p) {
        int j = p * 16 + (t >> 3);
        if (j < cnt) {
          int s = srcs[j];
          float e = leaky(AL[s * 16 + ha] + ald_sh[ha], LEAKY_ATT);
          wsh[j][ha] = __expf(e);
        }
      }
    }
    __syncthreads();

    // phase B: gather + accumulate
    for (int jj = 0; jj < cnt; jj += 4) {
      int e0 = jj + slot;
      if (e0 < cnt) {
        int s = srcs[e0];
        float w = wsh[e0][hd];
        uint2 q = *reinterpret_cast<const uint2*>(&XSb[(size_t)s * 128 + c0]);
        float f0 = __uint_as_float(q.x << 16);
        float f1 = __uint_as_float(q.x & 0xffff0000u);
        float f2 = __uint_as_float(q.y << 16);
        float f3 = __uint_as_float(q.y & 0xffff0000u);
        acc.x += w * f0;
        acc.y += w * f1;
        acc.z += w * f2;
        acc.w += w * f3;
        den += w;
      }
    }
    __syncthreads();
  }

  accsh[slot][lane] = acc;
  densh[slot][lane] = den;
  __syncthreads();

  if (t < 32) {
    int l = t;
    int h2 = l >> 2;
    float4 o = accsh[0][l];
    float4 o1 = accsh[1][l];
    float4 o2 = accsh[2][l];
    float4 o3 = accsh[3][l];
    o.x += o1.x + o2.x + o3.x;
    o.y += o1.y + o2.y + o3.y;
    o.z += o1.z + o2.z + o3.z;
    o.w += o1.w + o2.w + o3.w;
    float dtot = densh[0][l] + densh[1][l] + densh[2][l] + densh[3][l];

    // self loop
    float w0 = __expf(leaky(AL[node * 16 + h2] + ald_sh[h2], LEAKY_ATT));
    uint2 q = *reinterpret_cast<const uint2*>(&XSb[(size_t)node * 128 + l * 4]);
    o.x += w0 * __uint_as_float(q.x << 16);
    o.y += w0 * __uint_as_float(q.x & 0xffff0000u);
    o.z += w0 * __uint_as_float(q.y << 16);
    o.w += w0 * __uint_as_float(q.y & 0xffff0000u);
    dtot += w0;

    float4 b = *reinterpret_cast<const float4*>(&bias[l * 4]);
    float inv = 1.f / dtot;
    float4 r;
    r.x = o.x * inv + b.x;
    r.y = o.y * inv + b.y;
    r.z = o.z * inv + b.z;
    r.w = o.w * inv + b.w;
    if (act) {
      r.x = leaky(r.x, LEAKY_ACT);
      r.y = leaky(r.y, LEAKY_ACT);
      r.z = leaky(r.z, LEAKY_ACT);
      r.w = leaky(r.w, LEAKY_ACT);
    }
    *reinterpret_cast<float4*>(&OUT[(size_t)node * 128 + l * 4]) = r;
  }
}

// ============================ layer 3 ============================
__global__ __launch_bounds__(256) void k_lin3(const float* __restrict__ X,
                                              const float* __restrict__ U,
                                              float* __restrict__ XSAL3, int n) {
  __shared__ float xt[64][128];
  int t = threadIdx.x;
  int row0 = blockIdx.x * 64;
  for (int i = t; i < 64 * 128; i += 256) {
    int r = i >> 7, c = i & 127;
    int gr = row0 + r;
    xt[r][c] = (gr < n) ? X[gr * 128 + c] : 0.f;
  }
  __syncthreads();
  int node = t >> 2;
  int j = t & 3;
  float a = 0.f;
  for (int k = 0; k < 128; ++k) a += xt[node][k] * U[k * 4 + j];
  int gr = row0 + node;
  if (gr < n) XSAL3[gr * 4 + j] = a;
}

__global__ __launch_bounds__(256) void k_agg3(const float* __restrict__ XSAL3,
                                              const int* __restrict__ rowptr,
                                              const int* __restrict__ col,
                                              const float* __restrict__ b3,
                                              float* __restrict__ out, int n) {
  int node = blockIdx.x * blockDim.x + threadIdx.x;
  if (node >= n) return;
  float4 self = *reinterpret_cast<const float4*>(&XSAL3[node * 4]);
  float ald = self.w;
  float e0 = leaky(self.z + ald, LEAKY_ATT);
  float w0 = __expf(e0);
  float den = w0;
  float a0 = w0 * self.x;
  float a1 = w0 * self.y;
  int end = rowptr[node + 1];
  for (int jj = rowptr[node]; jj < end; ++jj) {
    int s = col[jj];
    float4 v = *reinterpret_cast<const float4*>(&XSAL3[s * 4]);
    float ee = leaky(v.z + ald, LEAKY_ATT);
    float w = __expf(ee);
    den += w;
    a0 += w * v.x;
    a1 += w * v.y;
  }
  out[node * 2 + 0] = a0 / den + b3[0];
  out[node * 2 + 1] = a1 / den + b3[1];
}

// ============================ launch ============================
extern "C" void kernel_launch(void* const* d_in, const int* in_sizes, int n_in,
                              void* d_out, int out_size, void* d_ws, size_t ws_size,
                              hipStream_t stream) {
  const float* x = (const float*)d_in[0];
  const int* ei = (const int*)d_in[1];
  const float* w1s = (const float*)d_in[2];
  const float* w1d = (const float*)d_in[3];
  const float* a1s = (const float*)d_in[4];
  const float* a1d = (const float*)d_in[5];
  const float* b1 = (const float*)d_in[6];
  const float* w2s = (const float*)d_in[7];
  const float* w2d = (const float*)d_in[8];
  const float* a2s = (const float*)d_in[9];
  const float* a2d = (const float*)d_in[10];
  const float* b2 = (const float*)d_in[11];
  const float* w3s = (const float*)d_in[12];
  const float* w3d = (const float*)d_in[13];
  const float* a3s = (const float*)d_in[14];
  const float* a3d = (const float*)d_in[15];
  const float* b3 = (const float*)d_in[16];

  int n = in_sizes[0] / 128;
  int e = in_sizes[1] / 2;
  const int* srcp = ei;
  const int* dstp = ei + e;

  size_t off = 0;
  auto alloc = [&](size_t bytes) -> void* {
    void* p = (char*)d_ws + off;
    off += (bytes + 255) & ~(size_t)255;
    return p;
  };
  int* deg = (int*)alloc((size_t)n * 4);
  int* cursor = (int*)alloc((size_t)n * 4);
  int* rowptr = (int*)alloc((size_t)(n + 1) * 4);
  int* partial = (int*)alloc((size_t)n * 4);
  int* bsum = (int*)alloc(1024 * 4);
  int* col = (int*)alloc((size_t)e * 4);
  float* vsd1 = (float*)alloc(128 * 16 * 4);
  float* vsd2 = (float*)alloc(128 * 16 * 4);
  float* u3 = (float*)alloc(128 * 4 * 4);
  float* al = (float*)alloc((size_t)n * 16 * 4);
  ushort* xsb = (ushort*)alloc((size_t)n * 128 * 2);
  float* ha = (float*)alloc((size_t)n * 128 * 4);
  float* xsal3 = (float*)alloc((size_t)n * 4 * 4);
  if (off > ws_size) return;

  int nb = (n + 255) / 256;

  hipMemsetAsync(deg, 0, (size_t)n * 4, stream);
  k_hist<<<2048, 256, 0, stream>>>(dstp, e, deg);
  k_scan1<<<nb, 256, 0, stream>>>(deg, n, partial, bsum);
  k_scan2<<<1, 512, 0, stream>>>(bsum, nb);
  k_scan3<<<nb, 256, 0, stream>>>(partial, deg, bsum, n, rowptr, cursor);
  k_scatter<<<2048, 256, 0, stream>>>(srcp, dstp, e, cursor, col);

  k_prep_vsd<<<128, 16, 0, stream>>>(w1s, w1d, a1s, a1d, vsd1);
  k_prep_vsd<<<128, 16, 0, stream>>>(w2s, w2d, a2s, a2d, vsd2);
  k_prep_u3<<<1, 128, 0, stream>>>(w3s, w3d, a3s, a3d, u3);

  int gb = (n + 63) / 64;
  // layer 1
  k_gemm_xs_al<<<gb, 256, 0, stream>>>(x, w1s, vsd1, xsb, al, n);
  k_gat_agg<<<n, 128, 0, stream>>>(xsb, al, rowptr, col, b1, ha, n, 1);
  // layer 2
  k_gemm_xs_al<<<gb, 256, 0, stream>>>(ha, w2s, vsd2, xsb, al, n);
  k_gat_agg<<<n, 128, 0, stream>>>(xsb, al, rowptr, col, b2, ha, n, 1);
  // layer 3
  k_lin3<<<gb, 256, 0, stream>>>(ha, u3, xsal3, n);
  k_agg3<<<(n + 255) / 256, 256, 0, stream>>>(xsal3, rowptr, col, b3, (float*)d_out, n);
}

// Round 3
// 491.818 us; speedup vs baseline: 1.4118x; 1.3127x over previous
//
#include <hip/hip_runtime.h>
#include <hip/hip_bf16.h>

#define LEAKY_ATT 0.2f
#define LEAKY_ACT 0.01f
#define BSHIFT 8
#define CH 4096

__device__ __forceinline__ float leaky(float x, float s) { return x >= 0.f ? x : s * x; }

__device__ __forceinline__ uint f2bf(float f) {
  __hip_bfloat16 h = __float2bfloat16(f);  // RTNE
  return (uint)*reinterpret_cast<ushort*>(&h);
}

// ============================ CSR build: two-level counting sort ============================
// P1: bucket histogram (bucket = dst>>8), LDS-aggregated
__global__ __launch_bounds__(256) void k_bhist(const int* __restrict__ dst, int e, int nb,
                                               int* __restrict__ bcnt) {
  __shared__ int cnt[512];
  for (int i = threadIdx.x; i < 512; i += 256) cnt[i] = 0;
  __syncthreads();
  for (int i = blockIdx.x * 256 + threadIdx.x; i < e; i += gridDim.x * 256)
    atomicAdd(&cnt[dst[i] >> BSHIFT], 1);
  __syncthreads();
  for (int i = threadIdx.x; i < nb; i += 256)
    if (cnt[i]) atomicAdd(&bcnt[i], cnt[i]);
}

// P2: exclusive scan of bucket counts -> bbase[nb+1], bcur (mutable copy)
__global__ __launch_bounds__(512) void k_bscan(const int* __restrict__ bcnt, int nb,
                                               int* __restrict__ bbase, int* __restrict__ bcur) {
  __shared__ int sh[512];
  int t = threadIdx.x;
  int orig = (t < nb) ? bcnt[t] : 0;
  sh[t] = orig;
  __syncthreads();
  for (int off = 1; off < 512; off <<= 1) {
    int v = (t >= off) ? sh[t - off] : 0;
    __syncthreads();
    sh[t] += v;
    __syncthreads();
  }
  if (t < nb) {
    int ex = sh[t] - orig;
    bbase[t] = ex;
    bcur[t] = ex;
    if (t == nb - 1) bbase[nb] = sh[t];
  }
}

// P3: scatter edges into bucket-contiguous regions as packed (loc<<20 | src)
__global__ __launch_bounds__(256) void k_bucket(const int* __restrict__ src,
                                                const int* __restrict__ dst, int e, int nb,
                                                int* __restrict__ bcur, uint* __restrict__ bpair) {
  __shared__ uint spair[CH];
  __shared__ ushort skey[CH];
  __shared__ ushort srank[CH];
  __shared__ int cnt[512];
  __shared__ int gb[512];
  int t = threadIdx.x;
  int c0 = blockIdx.x * CH;
  int cn = min(CH, e - c0);
  if (cn <= 0) return;
  for (int i = t; i < 512; i += 256) cnt[i] = 0;
  __syncthreads();
  for (int i = t; i < cn; i += 256) {
    int s = src[c0 + i];
    int d = dst[c0 + i];
    int k = d >> BSHIFT;
    spair[i] = ((uint)(d & ((1 << BSHIFT) - 1)) << 20) | (uint)s;
    skey[i] = (ushort)k;
    srank[i] = (ushort)atomicAdd(&cnt[k], 1);
  }
  __syncthreads();
  for (int k = t; k < nb; k += 256)
    gb[k] = cnt[k] ? atomicAdd(&bcur[k], cnt[k]) : 0;
  __syncthreads();
  for (int i = t; i < cn; i += 256) {
    bpair[gb[skey[i]] + srank[i]] = spair[i];
  }
}

// P4: per-bucket CSR finalize (degrees, scan, rowptr, col) — all LDS
__global__ __launch_bounds__(256) void k_csr(const uint* __restrict__ bpair,
                                             const int* __restrict__ bbase, int n,
                                             int* __restrict__ rowptr, int* __restrict__ col) {
  __shared__ int deg[256];
  __shared__ int cur[256];
  int b = blockIdx.x, t = threadIdx.x;
  int e0 = bbase[b], e1 = bbase[b + 1];
  deg[t] = 0;
  __syncthreads();
  for (int i = e0 + t; i < e1; i += 256)
    atomicAdd(&deg[bpair[i] >> 20], 1);
  __syncthreads();
  int v = deg[t];
  cur[t] = v;
  __syncthreads();
  for (int off = 1; off < 256; off <<= 1) {
    int u = (t >= off) ? cur[t - off] : 0;
    __syncthreads();
    cur[t] += u;
    __syncthreads();
  }
  int incl = cur[t];
  int gnode = b * 256 + t;
  if (gnode < n) rowptr[gnode + 1] = e0 + incl;
  if (b == 0 && t == 0) rowptr[0] = 0;
  __syncthreads();
  cur[t] = e0 + incl - v;  // exclusive start for this node
  __syncthreads();
  for (int i = e0 + t; i < e1; i += 256) {
    uint pk = bpair[i];
    int loc = pk >> 20;
    int p = atomicAdd(&cur[loc], 1);
    col[p] = (int)(pk & 0xFFFFFu);
  }
}

// ============================ weight prep ============================
__global__ void k_prep_vsd(const float* __restrict__ wsrc, const float* __restrict__ wdst,
                           const float* __restrict__ asrc, const float* __restrict__ adst,
                           float* __restrict__ vsd) {
  int k = blockIdx.x;   // 0..127
  int i = threadIdx.x;  // 0..15
  float s = 0.f;
  if (i < 8) {
    for (int c = 0; c < 16; ++c) s += wsrc[k * 128 + i * 16 + c] * asrc[i * 16 + c];
  } else {
    int h = i - 8;
    for (int c = 0; c < 16; ++c) s += wdst[k * 128 + h * 16 + c] * adst[h * 16 + c];
  }
  vsd[k * 16 + i] = s;
}

__global__ void k_prep_u3(const float* __restrict__ w3s, const float* __restrict__ w3d,
                          const float* __restrict__ a3s, const float* __restrict__ a3d,
                          float* __restrict__ U) {
  int k = blockIdx.x * blockDim.x + threadIdx.x;
  if (k >= 128) return;
  U[k * 4 + 0] = w3s[k * 2 + 0];
  U[k * 4 + 1] = w3s[k * 2 + 1];
  U[k * 4 + 2] = w3s[k * 2 + 0] * a3s[0] + w3s[k * 2 + 1] * a3s[1];
  U[k * 4 + 3] = w3d[k * 2 + 0] * a3d[0] + w3d[k * 2 + 1] * a3d[1];
}

// ============================ layer 1/2 linear: XSb(bf16) = X@W, AL = X@vsd ============================
__global__ __launch_bounds__(256) void k_gemm_xs_al(const float* __restrict__ X,
                                                    const float* __restrict__ W,
                                                    const float* __restrict__ VSD,
                                                    ushort* __restrict__ XSb,
                                                    float* __restrict__ AL, int n) {
  __shared__ float xt[64][128];  // 32 KB
  int t = threadIdx.x;
  int row0 = blockIdx.x * 64;
  for (int i = t; i < 64 * 128; i += 256) {
    int r = i >> 7, c = i & 127;
    int gr = row0 + r;
    xt[r][c] = (gr < n) ? X[gr * 128 + c] : 0.f;
  }
  __syncthreads();

  int c0 = (t & 31) * 4;
  int r0 = (t >> 5) * 8;
  float acc[8][4] = {};
  for (int k = 0; k < 128; ++k) {
    float4 wv = *reinterpret_cast<const float4*>(&W[k * 128 + c0]);
#pragma unroll
    for (int i = 0; i < 8; ++i) {
      float xv = xt[r0 + i][k];
      acc[i][0] += xv * wv.x;
      acc[i][1] += xv * wv.y;
      acc[i][2] += xv * wv.z;
      acc[i][3] += xv * wv.w;
    }
  }
#pragma unroll
  for (int i = 0; i < 8; ++i) {
    int gr = row0 + r0 + i;
    if (gr < n) {
      uint lo = f2bf(acc[i][0]) | (f2bf(acc[i][1]) << 16);
      uint hi = f2bf(acc[i][2]) | (f2bf(acc[i][3]) << 16);
      *reinterpret_cast<uint2*>(&XSb[(size_t)gr * 128 + c0]) = make_uint2(lo, hi);
    }
  }

  // attention logits
  int node = t >> 2;
  int j0 = (t & 3) * 4;
  float a[4] = {};
  for (int k = 0; k < 128; ++k) {
    float xv = xt[node][k];
#pragma unroll
    for (int j = 0; j < 4; ++j) a[j] += xv * VSD[k * 16 + j0 + j];
  }
  int gr = row0 + node;
  if (gr < n) {
#pragma unroll
    for (int j = 0; j < 4; ++j) AL[gr * 16 + j0 + j] = a[j];
  }
}

// ============================ layer 1/2 aggregation ============================
__global__ __launch_bounds__(128) void k_gat_agg(const ushort* __restrict__ XSb,
                                                 const float* __restrict__ AL,
                                                 const int* __restrict__ rowptr,
                                                 const int* __restrict__ col,
                                                 const float* __restrict__ bias,
                                                 float* __restrict__ OUT, int n, int act) {
  int node = blockIdx.x;
  int t = threadIdx.x;
  int slot = t >> 5;
  int lane = t & 31;
  int c0 = lane * 4;
  int hd = lane >> 2;  // c0/16

  __shared__ int srcs[32];
  __shared__ float wsh[32][8];
  __shared__ float4 accsh[4][32];
  __shared__ float densh[4][32];
  __shared__ float ald_sh[8];

  if (t < 8) ald_sh[t] = AL[node * 16 + 8 + t];
  __syncthreads();

  float4 acc = make_float4(0.f, 0.f, 0.f, 0.f);
  float den = 0.f;

  int beg = rowptr[node], end = rowptr[node + 1];
  for (int base = beg; base < end; base += 32) {
    int cnt = min(32, end - base);
    if (t < cnt) srcs[t] = col[base + t];
    __syncthreads();

    // phase A: weights
    {
      int ha = t & 7;
#pragma unroll
      for (int p = 0; p < 2; ++p) {
        int j = p * 16 + (t >> 3);
        if (j < cnt) {
          int s = srcs[j];
          float e = leaky(AL[s * 16 + ha] + ald_sh[ha], LEAKY_ATT);
          wsh[j][ha] = __expf(e);
        }
      }
    }
    __syncthreads();

    // phase B: gather + accumulate
    for (int jj = 0; jj < cnt; jj += 4) {
      int e0 = jj + slot;
      if (e0 < cnt) {
        int s = srcs[e0];
        float w = wsh[e0][hd];
        uint2 q = *reinterpret_cast<const uint2*>(&XSb[(size_t)s * 128 + c0]);
        float f0 = __uint_as_float(q.x << 16);
        float f1 = __uint_as_float(q.x & 0xffff0000u);
        float f2 = __uint_as_float(q.y << 16);
        float f3 = __uint_as_float(q.y & 0xffff0000u);
        acc.x += w * f0;
        acc.y += w * f1;
        acc.z += w * f2;
        acc.w += w * f3;
        den += w;
      }
    }
    __syncthreads();
  }

  accsh[slot][lane] = acc;
  densh[slot][lane] = den;
  __syncthreads();

  if (t < 32) {
    int l = t;
    int h2 = l >> 2;
    float4 o = accsh[0][l];
    float4 o1 = accsh[1][l];
    float4 o2 = accsh[2][l];
    float4 o3 = accsh[3][l];
    o.x += o1.x + o2.x + o3.x;
    o.y += o1.y + o2.y + o3.y;
    o.z += o1.z + o2.z + o3.z;
    o.w += o1.w + o2.w + o3.w;
    float dtot = densh[0][l] + densh[1][l] + densh[2][l] + densh[3][l];

    // self loop
    float w0 = __expf(leaky(AL[node * 16 + h2] + ald_sh[h2], LEAKY_ATT));
    uint2 q = *reinterpret_cast<const uint2*>(&XSb[(size_t)node * 128 + l * 4]);
    o.x += w0 * __uint_as_float(q.x << 16);
    o.y += w0 * __uint_as_float(q.x & 0xffff0000u);
    o.z += w0 * __uint_as_float(q.y << 16);
    o.w += w0 * __uint_as_float(q.y & 0xffff0000u);
    dtot += w0;

    float4 b = *reinterpret_cast<const float4*>(&bias[l * 4]);
    float inv = 1.f / dtot;
    float4 r;
    r.x = o.x * inv + b.x;
    r.y = o.y * inv + b.y;
    r.z = o.z * inv + b.z;
    r.w = o.w * inv + b.w;
    if (act) {
      r.x = leaky(r.x, LEAKY_ACT);
      r.y = leaky(r.y, LEAKY_ACT);
      r.z = leaky(r.z, LEAKY_ACT);
      r.w = leaky(r.w, LEAKY_ACT);
    }
    *reinterpret_cast<float4*>(&OUT[(size_t)node * 128 + l * 4]) = r;
  }
}

// ============================ layer 3 ============================
__global__ __launch_bounds__(256) void k_lin3(const float* __restrict__ X,
                                              const float* __restrict__ U,
                                              float* __restrict__ XSAL3, int n) {
  __shared__ float xt[64][128];
  int t = threadIdx.x;
  int row0 = blockIdx.x * 64;
  for (int i = t; i < 64 * 128; i += 256) {
    int r = i >> 7, c = i & 127;
    int gr = row0 + r;
    xt[r][c] = (gr < n) ? X[gr * 128 + c] : 0.f;
  }
  __syncthreads();
  int node = t >> 2;
  int j = t & 3;
  float a = 0.f;
  for (int k = 0; k < 128; ++k) a += xt[node][k] * U[k * 4 + j];
  int gr = row0 + node;
  if (gr < n) XSAL3[gr * 4 + j] = a;
}

__global__ __launch_bounds__(256) void k_agg3(const float* __restrict__ XSAL3,
                                              const int* __restrict__ rowptr,
                                              const int* __restrict__ col,
                                              const float* __restrict__ b3,
                                              float* __restrict__ out, int n) {
  int node = blockIdx.x * blockDim.x + threadIdx.x;
  if (node >= n) return;
  float4 self = *reinterpret_cast<const float4*>(&XSAL3[node * 4]);
  float ald = self.w;
  float e0 = leaky(self.z + ald, LEAKY_ATT);
  float w0 = __expf(e0);
  float den = w0;
  float a0 = w0 * self.x;
  float a1 = w0 * self.y;
  int end = rowptr[node + 1];
  for (int jj = rowptr[node]; jj < end; ++jj) {
    int s = col[jj];
    float4 v = *reinterpret_cast<const float4*>(&XSAL3[s * 4]);
    float ee = leaky(v.z + ald, LEAKY_ATT);
    float w = __expf(ee);
    den += w;
    a0 += w * v.x;
    a1 += w * v.y;
  }
  out[node * 2 + 0] = a0 / den + b3[0];
  out[node * 2 + 1] = a1 / den + b3[1];
}

// ============================ launch ============================
extern "C" void kernel_launch(void* const* d_in, const int* in_sizes, int n_in,
                              void* d_out, int out_size, void* d_ws, size_t ws_size,
                              hipStream_t stream) {
  const float* x = (const float*)d_in[0];
  const int* ei = (const int*)d_in[1];
  const float* w1s = (const float*)d_in[2];
  const float* w1d = (const float*)d_in[3];
  const float* a1s = (const float*)d_in[4];
  const float* a1d = (const float*)d_in[5];
  const float* b1 = (const float*)d_in[6];
  const float* w2s = (const float*)d_in[7];
  const float* w2d = (const float*)d_in[8];
  const float* a2s = (const float*)d_in[9];
  const float* a2d = (const float*)d_in[10];
  const float* b2 = (const float*)d_in[11];
  const float* w3s = (const float*)d_in[12];
  const float* w3d = (const float*)d_in[13];
  const float* a3s = (const float*)d_in[14];
  const float* a3d = (const float*)d_in[15];
  const float* b3 = (const float*)d_in[16];

  int n = in_sizes[0] / 128;
  int e = in_sizes[1] / 2;
  const int* srcp = ei;
  const int* dstp = ei + e;

  int nb = (n + 255) >> BSHIFT;
  if (nb > 512) return;               // structure assumes n <= 131072
  if (n >= (1 << 20)) return;         // pack assumes src < 2^20

  size_t off = 0;
  auto alloc = [&](size_t bytes) -> void* {
    void* p = (char*)d_ws + off;
    off += (bytes + 255) & ~(size_t)255;
    return p;
  };
  int* bcnt = (int*)alloc((size_t)(nb) * 4);
  int* bbase = (int*)alloc((size_t)(nb + 1) * 4);
  int* bcur = (int*)alloc((size_t)nb * 4);
  uint* bpair = (uint*)alloc((size_t)e * 4);
  int* rowptr = (int*)alloc((size_t)(n + 1) * 4);
  int* col = (int*)alloc((size_t)e * 4);
  float* vsd1 = (float*)alloc(128 * 16 * 4);
  float* vsd2 = (float*)alloc(128 * 16 * 4);
  float* u3 = (float*)alloc(128 * 4 * 4);
  float* al = (float*)alloc((size_t)n * 16 * 4);
  ushort* xsb = (ushort*)alloc((size_t)n * 128 * 2);
  float* ha = (float*)alloc((size_t)n * 128 * 4);
  float* xsal3 = (float*)alloc((size_t)n * 4 * 4);
  if (off > ws_size) return;

  // CSR build via two-level counting sort
  hipMemsetAsync(bcnt, 0, (size_t)nb * 4, stream);
  k_bhist<<<512, 256, 0, stream>>>(dstp, e, nb, bcnt);
  k_bscan<<<1, 512, 0, stream>>>(bcnt, nb, bbase, bcur);
  k_bucket<<<(e + CH - 1) / CH, 256, 0, stream>>>(srcp, dstp, e, nb, bcur, bpair);
  k_csr<<<nb, 256, 0, stream>>>(bpair, bbase, n, rowptr, col);

  // weight prep
  k_prep_vsd<<<128, 16, 0, stream>>>(w1s, w1d, a1s, a1d, vsd1);
  k_prep_vsd<<<128, 16, 0, stream>>>(w2s, w2d, a2s, a2d, vsd2);
  k_prep_u3<<<1, 128, 0, stream>>>(w3s, w3d, a3s, a3d, u3);

  int gb = (n + 63) / 64;
  // layer 1
  k_gemm_xs_al<<<gb, 256, 0, stream>>>(x, w1s, vsd1, xsb, al, n);
  k_gat_agg<<<n, 128, 0, stream>>>(xsb, al, rowptr, col, b1, ha, n, 1);
  // layer 2
  k_gemm_xs_al<<<gb, 256, 0, stream>>>(ha, w2s, vsd2, xsb, al, n);
  k_gat_agg<<<n, 128, 0, stream>>>(xsb, al, rowptr, col, b2, ha, n, 1);
  // layer 3
  k_lin3<<<gb, 256, 0, stream>>>(ha, u3, xsal3, n);
  k_agg3<<<(n + 255) / 256, 256, 0, stream>>>(xsal3, rowptr, col, b3, (float*)d_out, n);
}